// Round 1
// baseline (5478.563 us; speedup 1.0000x reference)
//
#include <hip/hip_runtime.h>
#include <hip/hip_bf16.h>
#include <stdint.h>

typedef unsigned int u32;
typedef unsigned long long u64;
typedef unsigned char u8;

// ---------------------------------------------------------------------------
// Reduction-order hypotheses for n[v] = sum_f image[v,f]^2 (must bit-match the
// XLA:CPU reference reduction to reproduce its sort order for near-ties):
//   H1: RW=8,  HALVING=1  -> stride-8 partials, shuffle-halving combine (XLA AVX2)
//   H2: RW=16, HALVING=1  -> stride-16 partials, halving (XLA AVX512 / unroll2)
//   H3: RW=8,  HALVING=0  -> stride-8 partials, numpy pairwise combine
//   H4: RW=1              -> pure serial left-to-right
// ---------------------------------------------------------------------------
#define RW 8
#define HALVING 1

// ---- K1: per-vertex squared norm ----
__global__ __launch_bounds__(256) void vnorm_kernel(const float* __restrict__ image,
                                                    float* __restrict__ nrm,
                                                    int V, int F) {
#pragma clang fp contract(off)
  const int gpv = 256 / RW;                // vertices per block
  int g = threadIdx.x / RW;
  int l = threadIdx.x % RW;
  int v = blockIdx.x * gpv + g;
  if (v >= V) return;
  const float* row = image + (size_t)v * F;
  int terms = F / RW;                      // 16 for F=128,RW=8
  float x = row[l];
  float a = x * x;
  for (int i = 1; i < terms; ++i) {
    float y = row[i * RW + l];
    a = a + y * y;                         // separate mul+add, no contraction
  }
#if RW > 1
#if HALVING
#pragma unroll
  for (int d = RW / 2; d >= 1; d >>= 1) a = a + __shfl_xor(a, d);
#else
#pragma unroll
  for (int d = 1; d < RW; d <<= 1) a = a + __shfl_xor(a, d);
#endif
#endif
  if (l == 0) nrm[v] = a;
}

// ---- K2: per-edge priority, sort key, boundary flag ----
__global__ __launch_bounds__(256) void edge_kernel(const float* __restrict__ nrm,
                                                   const float* __restrict__ vs,
                                                   const int* __restrict__ edges,
                                                   u64* __restrict__ keys,
                                                   u8* __restrict__ bnd,
                                                   float* __restrict__ out_sq,
                                                   int E, int Npad) {
#pragma clang fp contract(off)
  int e = blockIdx.x * 256 + threadIdx.x;
  if (e >= Npad) return;
  u64 key = ~0ull;                         // sentinel sorts last
  if (e < E) {
    int v0 = edges[e], v1 = edges[E + e];
    float sq = nrm[v0] + nrm[v1];          // commutative: order-safe
    out_sq[e] = sq;
    key = ((u64)__float_as_uint(sq) << 32) | (u32)e;
    float ax = vs[2 * v0], ay = vs[2 * v0 + 1];
    float bx = vs[2 * v1], by = vs[2 * v1 + 1];
    const float lo = 0.01f, hi = 0.99f;    // EPSILON, 1-EPSILON as f32
    bool b = (ax < lo) | (ax > hi) | (ay < lo) | (ay > hi)
           | (bx < lo) | (bx > hi) | (by < lo) | (by > hi);
    bnd[e] = b ? 1 : 0;
  }
  keys[e] = key;
}

// ---- K3: radix histogram (256 bins, 1024 items/block) ----
__global__ __launch_bounds__(256) void hist_kernel(const u64* __restrict__ src,
                                                   u32* __restrict__ hist,
                                                   int shift, int nBlocks) {
  __shared__ u32 c[256];
  c[threadIdx.x] = 0;
  __syncthreads();
  int base = blockIdx.x * 1024;
  for (int k = 0; k < 4; ++k) {
    u64 key = src[base + k * 256 + threadIdx.x];
    int d = (int)((key >> shift) & 255);
    atomicAdd(&c[d], 1u);
  }
  __syncthreads();
  hist[(size_t)threadIdx.x * nBlocks + blockIdx.x] = c[threadIdx.x];
}

// ---- K4: global exclusive scan of digit-major histogram (1 block) ----
__global__ __launch_bounds__(256) void scan_kernel(u32* __restrict__ hist, int nBlocks) {
  __shared__ u32 tot[256];
  int d = threadIdx.x;
  u32 s = 0;
  for (int b = 0; b < nBlocks; ++b) s += hist[(size_t)d * nBlocks + b];
  tot[d] = s;
  __syncthreads();
  if (d == 0) {
    u32 run = 0;
    for (int i = 0; i < 256; ++i) { u32 t = tot[i]; tot[i] = run; run += t; }
  }
  __syncthreads();
  u32 run = tot[d];
  for (int b = 0; b < nBlocks; ++b) {
    u32 t = hist[(size_t)d * nBlocks + b];
    hist[(size_t)d * nBlocks + b] = run;
    run += t;
  }
}

// ---- K5: stable radix scatter ----
__global__ __launch_bounds__(256) void scatter_kernel(const u64* __restrict__ src,
                                                      u64* __restrict__ dst,
                                                      const u32* __restrict__ hist,
                                                      int shift, int nBlocks) {
  __shared__ u32 off[256];
  __shared__ u32 cw[4][256];
  int tid = threadIdx.x;
  off[tid] = hist[(size_t)tid * nBlocks + blockIdx.x];
  int lane = tid & 63, w = tid >> 6;
  int base = blockIdx.x * 1024;
  for (int k = 0; k < 4; ++k) {
    cw[0][tid] = 0; cw[1][tid] = 0; cw[2][tid] = 0; cw[3][tid] = 0;
    __syncthreads();
    u64 key = src[base + k * 256 + tid];
    int d = (int)((key >> shift) & 255);
    // 64-lane match mask for 8-bit digit via 8 ballots
    u64 m = ~0ull;
#pragma unroll
    for (int bit = 0; bit < 8; ++bit) {
      u64 bl = __ballot((d >> bit) & 1);
      m &= ((d >> bit) & 1) ? bl : ~bl;
    }
    u32 riw = (u32)__popcll(m & ((1ull << lane) - 1ull));  // stable rank in wave
    if (riw == 0) cw[w][d] = (u32)__popcll(m);             // per-wave digit count
    __syncthreads();
    u32 r = riw;
    for (int ww = 0; ww < w; ++ww) r += cw[ww][d];
    dst[off[d] + r] = key;
    __syncthreads();
    off[tid] += cw[0][tid] + cw[1][tid] + cw[2][tid] + cw[3][tid];
    __syncthreads();
  }
}

// ---- K6: serial greedy collapse, one wave, mask in LDS ----
__global__ __launch_bounds__(64) void collapse_kernel(const u64* __restrict__ sorted,
                                                      const int* __restrict__ edges,
                                                      const u8* __restrict__ bnd,
                                                      const int* __restrict__ tgt,
                                                      float* __restrict__ out,
                                                      int V, int E) {
  __shared__ u8 mask[50048];
  int lane = threadIdx.x;
  for (int i = lane; i < V; i += 64) mask[i] = 1;
  int target = tgt[0];
  int cnt = V;
  __syncthreads();
  int nch = (E + 63) / 64;
  // preload chunk 0
  int v0 = 0, v1 = 0, nb = 1;
  if (lane < E) {
    u32 idx = (u32)sorted[lane];
    v0 = edges[idx]; v1 = edges[E + idx]; nb = bnd[idx];
  }
  for (int c = 0; c < nch; ++c) {
    if (cnt <= target) break;              // no further mask/count changes possible
    // prefetch next chunk (hides HBM/L2 latency under the readlane chain)
    int nv0 = 0, nv1 = 0, nnb = 1;
    int g2 = (c + 1) * 64 + lane;
    if (c + 1 < nch && g2 < E) {
      u32 idx = (u32)sorted[g2];
      nv0 = edges[idx]; nv1 = edges[E + idx]; nnb = bnd[idx];
    }
    int a0 = mask[v0];
    int a1 = mask[v1];
    int myDo = 0;
    // exact sequential semantics across the 64 lanes of this chunk
#pragma unroll
    for (int j = 0; j < 64; ++j) {
      int cand = (cnt > target) & a0 & a1 & (nb ^ 1);
      int dj = __builtin_amdgcn_readlane(cand, j);   // uniform: lane j's decision
      int kv = __builtin_amdgcn_readlane(v1, j);     // uniform: its killed vertex
      cnt -= dj;
      a0 &= 1 ^ (dj & (v0 == kv));
      a1 &= 1 ^ (dj & (v1 == kv));
      myDo = (lane == j) ? dj : myDo;
    }
    if (myDo) mask[v1] = 0;
    __syncthreads();
    v0 = nv0; v1 = nv1; nb = nnb;
  }
  __syncthreads();
  for (int i = lane; i < V; i += 64) out[E + i] = mask[i] ? 1.0f : 0.0f;
  if (lane == 0) out[E + V] = (float)cnt;
}

extern "C" void kernel_launch(void* const* d_in, const int* in_sizes, int n_in,
                              void* d_out, int out_size, void* d_ws, size_t ws_size,
                              hipStream_t stream) {
  const float* image = (const float*)d_in[0];
  const float* vs    = (const float*)d_in[1];
  const int*   edges = (const int*)d_in[2];
  const int*   tgt   = (const int*)d_in[3];
  int V = in_sizes[1] / 2;             // 50000
  int E = in_sizes[2] / 2;             // 150000
  int F = in_sizes[0] / V;             // 128
  int Npad = ((E + 1023) / 1024) * 1024;   // 150528
  int B = Npad / 1024;                 // 147 radix blocks

  // workspace layout (~2.9 MB)
  char* ws = (char*)d_ws;
  u64* keysA = (u64*)ws;
  u64* keysB = (u64*)(ws + (size_t)Npad * 8);
  float* nrm = (float*)(ws + (size_t)Npad * 16);
  u8*  bnd   = (u8*) (ws + (size_t)Npad * 16 + (size_t)V * 4);
  u32* hist  = (u32*)(ws + (size_t)Npad * 16 + (size_t)V * 4 + (size_t)Npad);
  float* out = (float*)d_out;

  int gpv = 256 / RW;
  vnorm_kernel<<<dim3((V + gpv - 1) / gpv), dim3(256), 0, stream>>>(image, nrm, V, F);
  edge_kernel<<<dim3(Npad / 256), dim3(256), 0, stream>>>(nrm, vs, edges, keysA, bnd, out, E, Npad);

  u64* src = keysA; u64* dst = keysB;
  for (int p = 0; p < 4; ++p) {
    int shift = 32 + 8 * p;            // stable LSD on the sq bits only
    hist_kernel<<<dim3(B), dim3(256), 0, stream>>>(src, hist, shift, B);
    scan_kernel<<<dim3(1), dim3(256), 0, stream>>>(hist, B);
    scatter_kernel<<<dim3(B), dim3(256), 0, stream>>>(src, dst, hist, shift, B);
    u64* t = src; src = dst; dst = t;
  }
  // after 4 passes result is back in keysA (== src)
  collapse_kernel<<<dim3(1), dim3(64), 0, stream>>>(src, edges, bnd, tgt, out, V, E);
}

// Round 2
// 1263.381 us; speedup vs baseline: 4.3364x; 4.3364x over previous
//
#include <hip/hip_runtime.h>
#include <hip/hip_bf16.h>
#include <stdint.h>

typedef unsigned int u32;
typedef unsigned long long u64;
typedef unsigned char u8;

// ---------------------------------------------------------------------------
// Reduction-order hypotheses for n[v] = sum_f image[v,f]^2 (bit-matches the
// XLA:CPU reference reduction; H1 verified PASS in round 1):
// ---------------------------------------------------------------------------
#define RW 8
#define HALVING 1

// ---- K1: per-vertex squared norm ----
__global__ __launch_bounds__(256) void vnorm_kernel(const float* __restrict__ image,
                                                    float* __restrict__ nrm,
                                                    int V, int F) {
#pragma clang fp contract(off)
  const int gpv = 256 / RW;                // vertices per block
  int g = threadIdx.x / RW;
  int l = threadIdx.x % RW;
  int v = blockIdx.x * gpv + g;
  if (v >= V) return;
  const float* row = image + (size_t)v * F;
  int terms = F / RW;                      // 16 for F=128,RW=8
  float x = row[l];
  float a = x * x;
  for (int i = 1; i < terms; ++i) {
    float y = row[i * RW + l];
    a = a + y * y;                         // separate mul+add, no contraction
  }
#if RW > 1
#if HALVING
#pragma unroll
  for (int d = RW / 2; d >= 1; d >>= 1) a = a + __shfl_xor(a, d);
#else
#pragma unroll
  for (int d = 1; d < RW; d <<= 1) a = a + __shfl_xor(a, d);
#endif
#endif
  if (l == 0) nrm[v] = a;
}

// ---- K2: per-edge priority, sort key, boundary flag ----
__global__ __launch_bounds__(256) void edge_kernel(const float* __restrict__ nrm,
                                                   const float* __restrict__ vs,
                                                   const int* __restrict__ edges,
                                                   u64* __restrict__ keys,
                                                   u8* __restrict__ bnd,
                                                   float* __restrict__ out_sq,
                                                   int E, int Npad) {
#pragma clang fp contract(off)
  int e = blockIdx.x * 256 + threadIdx.x;
  if (e >= Npad) return;
  u64 key = ~0ull;                         // sentinel sorts last
  if (e < E) {
    int v0 = edges[e], v1 = edges[E + e];
    float sq = nrm[v0] + nrm[v1];          // commutative: order-safe
    out_sq[e] = sq;
    key = ((u64)__float_as_uint(sq) << 32) | (u32)e;
    float ax = vs[2 * v0], ay = vs[2 * v0 + 1];
    float bx = vs[2 * v1], by = vs[2 * v1 + 1];
    const float lo = 0.01f, hi = 0.99f;    // EPSILON, 1-EPSILON as f32
    bool b = (ax < lo) | (ax > hi) | (ay < lo) | (ay > hi)
           | (bx < lo) | (bx > hi) | (by < lo) | (by > hi);
    bnd[e] = b ? 1 : 0;
  }
  keys[e] = key;
}

// ---- K3: radix histogram (256 bins, 1024 items/block) ----
__global__ __launch_bounds__(256) void hist_kernel(const u64* __restrict__ src,
                                                   u32* __restrict__ hist,
                                                   int shift, int nBlocks) {
  __shared__ u32 c[256];
  c[threadIdx.x] = 0;
  __syncthreads();
  int base = blockIdx.x * 1024;
  for (int k = 0; k < 4; ++k) {
    u64 key = src[base + k * 256 + threadIdx.x];
    int d = (int)((key >> shift) & 255);
    atomicAdd(&c[d], 1u);
  }
  __syncthreads();
  hist[(size_t)threadIdx.x * nBlocks + blockIdx.x] = c[threadIdx.x];
}

// ---- K4: global exclusive scan of digit-major histogram (1 block) ----
__global__ __launch_bounds__(256) void scan_kernel(u32* __restrict__ hist, int nBlocks) {
  __shared__ u32 tot[256];
  int d = threadIdx.x;
  u32 s = 0;
  for (int b = 0; b < nBlocks; ++b) s += hist[(size_t)d * nBlocks + b];
  tot[d] = s;
  __syncthreads();
  if (d == 0) {
    u32 run = 0;
    for (int i = 0; i < 256; ++i) { u32 t = tot[i]; tot[i] = run; run += t; }
  }
  __syncthreads();
  u32 run = tot[d];
  for (int b = 0; b < nBlocks; ++b) {
    u32 t = hist[(size_t)d * nBlocks + b];
    hist[(size_t)d * nBlocks + b] = run;
    run += t;
  }
}

// ---- K5: stable radix scatter ----
__global__ __launch_bounds__(256) void scatter_kernel(const u64* __restrict__ src,
                                                      u64* __restrict__ dst,
                                                      const u32* __restrict__ hist,
                                                      int shift, int nBlocks) {
  __shared__ u32 off[256];
  __shared__ u32 cw[4][256];
  int tid = threadIdx.x;
  off[tid] = hist[(size_t)tid * nBlocks + blockIdx.x];
  int lane = tid & 63, w = tid >> 6;
  int base = blockIdx.x * 1024;
  for (int k = 0; k < 4; ++k) {
    cw[0][tid] = 0; cw[1][tid] = 0; cw[2][tid] = 0; cw[3][tid] = 0;
    __syncthreads();
    u64 key = src[base + k * 256 + tid];
    int d = (int)((key >> shift) & 255);
    u64 m = ~0ull;
#pragma unroll
    for (int bit = 0; bit < 8; ++bit) {
      u64 bl = __ballot((d >> bit) & 1);
      m &= ((d >> bit) & 1) ? bl : ~bl;
    }
    u32 riw = (u32)__popcll(m & ((1ull << lane) - 1ull));  // stable rank in wave
    if (riw == 0) cw[w][d] = (u32)__popcll(m);             // per-wave digit count
    __syncthreads();
    u32 r = riw;
    for (int ww = 0; ww < w; ++ww) r += cw[ww][d];
    dst[off[d] + r] = key;
    __syncthreads();
    off[tid] += cw[0][tid] + cw[1][tid] + cw[2][tid] + cw[3][tid];
    __syncthreads();
  }
}

// ---- K6: serial greedy collapse, one wave, mask in LDS ----
// Fast path per 64-edge chunk: exact shared-vertex detection via tag
// write/readback in the mask array itself; clean chunks decided fully in
// parallel; duplicate chunks serialize only over the flagged lanes; the
// single threshold-sensitive chunk falls back to the exact 64-step loop.
__global__ __launch_bounds__(64) void collapse_kernel(const u64* __restrict__ sorted,
                                                      const int* __restrict__ edges,
                                                      const u8* __restrict__ bnd,
                                                      const int* __restrict__ tgt,
                                                      float* __restrict__ out,
                                                      int V, int E) {
  __shared__ u8 mask[50048];
  int lane = threadIdx.x;
  for (int i = lane; i < V; i += 64) mask[i] = 1;
  int target = tgt[0];
  int cnt = V;
  __syncthreads();
  int nch = (E + 63) / 64;
  // preload chunk 0
  int v0 = 0, v1 = 0, nb = 1;
  if (lane < E) {
    u32 idx = (u32)sorted[lane];
    v0 = edges[idx]; v1 = edges[E + idx]; nb = bnd[idx];
  }
  for (int c = 0; c < nch; ++c) {
    if (cnt <= target) break;
    // prefetch next chunk (hides HBM/L2 latency under this chunk's LDS chain)
    int nv0 = 0, nv1 = 0, nnb = 1;
    int g2 = (c + 1) * 64 + lane;
    if (c + 1 < nch && g2 < E) {
      u32 idx = (u32)sorted[g2];
      nv0 = edges[idx]; nv1 = edges[E + idx]; nnb = bnd[idx];
    }
    int m0 = mask[v0];
    int m1 = mask[v1];
    int cand = m0 & m1 & (nb ^ 1);
    // ---- tag round 1: detect any lane pair sharing a vertex ----
    u8 tag = (u8)(lane + 2);
    mask[v0] = tag;
    mask[v1] = tag;
    asm volatile("" ::: "memory");   // stop store->load forwarding of tags
    int r0 = mask[v0];
    int r1 = mask[v1];
    int mism = (r0 != (int)tag) | (r1 != (int)tag);
    u64 flags = __ballot(mism);
    int doit, K;
    if (flags != 0) {
      // ---- tag round 2: losers rewrite so winners get flagged too (closure) ----
      if (mism) { mask[v0] = tag; mask[v1] = tag; }
      asm volatile("" ::: "memory");
      r0 = mask[v0];
      r1 = mask[v1];
      mism |= (r0 != (int)tag) | (r1 != (int)tag);
      flags = __ballot(mism);
    }
    // ---- restore true mask values (lanes sharing a vertex restore equal values) ----
    mask[(u32)v0] = (u8)m0;
    mask[(u32)v1] = (u8)m1;
    asm volatile("" ::: "memory");
    if (flags == 0) {
      doit = cand;
      K = (int)__popcll(__ballot(doit));
    } else {
      int pdo = cand & (mism ^ 1);               // unflagged lanes: independent
      K = (int)__popcll(__ballot(pdo));
      int fa0 = m0, fa1 = m1, sdo = 0;
      u64 fm = flags;
      while (fm) {                               // serial over flagged lanes only
        int j = (int)__builtin_ctzll(fm);
        fm &= fm - 1;
        int ccur = fa0 & fa1 & (nb ^ 1);
        int d = __builtin_amdgcn_readlane(ccur, j);
        int kv = __builtin_amdgcn_readlane(v1, j);
        K += d;
        fa0 &= 1 ^ (d & (v0 == kv));
        fa1 &= 1 ^ (d & (v1 == kv));
        sdo = (lane == j) ? d : sdo;
      }
      doit = mism ? sdo : pdo;
    }
    if (cnt - K >= target) {                     // bulk apply is order-exact
      if (doit) mask[v1] = 0;
      cnt -= K;
    } else {
      // threshold-sensitive chunk (happens once): exact sequential semantics
      int a0 = m0, a1 = m1, myDo = 0;
#pragma unroll
      for (int j = 0; j < 64; ++j) {
        int candj = (cnt > target) & a0 & a1 & (nb ^ 1);
        int dj = __builtin_amdgcn_readlane(candj, j);
        int kv = __builtin_amdgcn_readlane(v1, j);
        cnt -= dj;
        a0 &= 1 ^ (dj & (v0 == kv));
        a1 &= 1 ^ (dj & (v1 == kv));
        myDo = (lane == j) ? dj : myDo;
      }
      if (myDo) mask[v1] = 0;
    }
    asm volatile("" ::: "memory");
    v0 = nv0; v1 = nv1; nb = nnb;
  }
  __syncthreads();
  for (int i = lane; i < V; i += 64) out[E + i] = mask[i] ? 1.0f : 0.0f;
  if (lane == 0) out[E + V] = (float)cnt;
}

extern "C" void kernel_launch(void* const* d_in, const int* in_sizes, int n_in,
                              void* d_out, int out_size, void* d_ws, size_t ws_size,
                              hipStream_t stream) {
  const float* image = (const float*)d_in[0];
  const float* vs    = (const float*)d_in[1];
  const int*   edges = (const int*)d_in[2];
  const int*   tgt   = (const int*)d_in[3];
  int V = in_sizes[1] / 2;             // 50000
  int E = in_sizes[2] / 2;             // 150000
  int F = in_sizes[0] / V;             // 128
  int Npad = ((E + 1023) / 1024) * 1024;   // 150528
  int B = Npad / 1024;                 // 147 radix blocks

  // workspace layout (~2.9 MB)
  char* ws = (char*)d_ws;
  u64* keysA = (u64*)ws;
  u64* keysB = (u64*)(ws + (size_t)Npad * 8);
  float* nrm = (float*)(ws + (size_t)Npad * 16);
  u8*  bnd   = (u8*) (ws + (size_t)Npad * 16 + (size_t)V * 4);
  u32* hist  = (u32*)(ws + (size_t)Npad * 16 + (size_t)V * 4 + (size_t)Npad);
  float* out = (float*)d_out;

  int gpv = 256 / RW;
  vnorm_kernel<<<dim3((V + gpv - 1) / gpv), dim3(256), 0, stream>>>(image, nrm, V, F);
  edge_kernel<<<dim3(Npad / 256), dim3(256), 0, stream>>>(nrm, vs, edges, keysA, bnd, out, E, Npad);

  u64* src = keysA; u64* dst = keysB;
  for (int p = 0; p < 4; ++p) {
    int shift = 32 + 8 * p;            // stable LSD on the sq bits only
    hist_kernel<<<dim3(B), dim3(256), 0, stream>>>(src, hist, shift, B);
    scan_kernel<<<dim3(1), dim3(256), 0, stream>>>(hist, B);
    scatter_kernel<<<dim3(B), dim3(256), 0, stream>>>(src, dst, hist, shift, B);
    u64* t = src; src = dst; dst = t;
  }
  // after 4 passes result is back in keysA (== src)
  collapse_kernel<<<dim3(1), dim3(64), 0, stream>>>(src, edges, bnd, tgt, out, V, E);
}

// Round 3
// 1025.480 us; speedup vs baseline: 5.3424x; 1.2320x over previous
//
#include <hip/hip_runtime.h>
#include <hip/hip_bf16.h>
#include <stdint.h>

typedef unsigned int u32;
typedef unsigned long long u64;
typedef unsigned char u8;
typedef unsigned short u16;

// ---------------------------------------------------------------------------
// Reduction order for n[v] = sum_f image[v,f]^2 bit-matches the XLA:CPU
// reference (H1: stride-8 partials + halving combine; verified PASS R1/R2).
// DO NOT change RW/HALVING: vertex_mask correctness depends on exact rounding.
// ---------------------------------------------------------------------------
#define RW 8
#define HALVING 1

// ---- K1: per-vertex squared norm ----
__global__ __launch_bounds__(256) void vnorm_kernel(const float* __restrict__ image,
                                                    float* __restrict__ nrm,
                                                    int V, int F) {
#pragma clang fp contract(off)
  const int gpv = 256 / RW;                // vertices per block
  int g = threadIdx.x / RW;
  int l = threadIdx.x % RW;
  int v = blockIdx.x * gpv + g;
  if (v >= V) return;
  const float* row = image + (size_t)v * F;
  int terms = F / RW;                      // 16 for F=128,RW=8
  float x = row[l];
  float a = x * x;
  for (int i = 1; i < terms; ++i) {
    float y = row[i * RW + l];
    a = a + y * y;                         // separate mul+add, no contraction
  }
#if RW > 1
#if HALVING
#pragma unroll
  for (int d = RW / 2; d >= 1; d >>= 1) a = a + __shfl_xor(a, d);
#else
#pragma unroll
  for (int d = 1; d < RW; d <<= 1) a = a + __shfl_xor(a, d);
#endif
#endif
  if (l == 0) nrm[v] = a;
}

// ---- K2: per-edge priority, sort key, boundary flag ----
__global__ __launch_bounds__(256) void edge_kernel(const float* __restrict__ nrm,
                                                   const float* __restrict__ vs,
                                                   const int* __restrict__ edges,
                                                   u64* __restrict__ keys,
                                                   u8* __restrict__ bnd,
                                                   float* __restrict__ out_sq,
                                                   int E, int Npad) {
#pragma clang fp contract(off)
  int e = blockIdx.x * 256 + threadIdx.x;
  if (e >= Npad) return;
  u64 key = ~0ull;                         // sentinel sorts last
  if (e < E) {
    int v0 = edges[e], v1 = edges[E + e];
    float sq = nrm[v0] + nrm[v1];          // commutative: order-safe
    out_sq[e] = sq;
    key = ((u64)__float_as_uint(sq) << 32) | (u32)e;
    float ax = vs[2 * v0], ay = vs[2 * v0 + 1];
    float bx = vs[2 * v1], by = vs[2 * v1 + 1];
    const float lo = 0.01f, hi = 0.99f;
    bool b = (ax < lo) | (ax > hi) | (ay < lo) | (ay > hi)
           | (bx < lo) | (bx > hi) | (by < lo) | (by > hi);
    bnd[e] = b ? 1 : 0;
  }
  keys[e] = key;
}

// ---- K3: radix histogram (256 bins, 1024 items/block) ----
__global__ __launch_bounds__(256) void hist_kernel(const u64* __restrict__ src,
                                                   u32* __restrict__ hist,
                                                   int shift, int nBlocks) {
  __shared__ u32 c[256];
  c[threadIdx.x] = 0;
  __syncthreads();
  int base = blockIdx.x * 1024;
  for (int k = 0; k < 4; ++k) {
    u64 key = src[base + k * 256 + threadIdx.x];
    int d = (int)((key >> shift) & 255);
    atomicAdd(&c[d], 1u);
  }
  __syncthreads();
  hist[(size_t)threadIdx.x * nBlocks + blockIdx.x] = c[threadIdx.x];
}

// ---- K4: flat exclusive scan of the [256][B] digit-major histogram ----
// One block, 1024 threads, hierarchical: per-thread serial chunk -> wave
// shfl scan -> cross-wave scan -> add back. Re-reads hist in pass 2 instead
// of caching in a runtime-indexed array (which would spill to scratch).
__global__ __launch_bounds__(1024) void scan_kernel(u32* __restrict__ hist, int n) {
  __shared__ u32 wsum[16];
  int tid = threadIdx.x;
  int K = (n + 1023) / 1024;
  int base = tid * K;
  u32 s = 0;
  for (int i = 0; i < K; ++i) {
    int g = base + i;
    if (g < n) s += hist[g];
  }
  int lane = tid & 63, wv = tid >> 6;
  u32 inc = s;
#pragma unroll
  for (int d = 1; d < 64; d <<= 1) {
    u32 t = __shfl_up(inc, d);
    if (lane >= d) inc += t;
  }
  if (lane == 63) wsum[wv] = inc;
  __syncthreads();
  if (wv == 0) {
    u32 w0 = (lane < 16) ? wsum[lane] : 0;
    u32 winc = w0;
#pragma unroll
    for (int d = 1; d < 16; d <<= 1) {
      u32 t = __shfl_up(winc, d);
      if (lane >= d) winc += t;
    }
    if (lane < 16) wsum[lane] = winc - w0;   // exclusive wave base
  }
  __syncthreads();
  u32 run = wsum[wv] + (inc - s);            // exclusive prefix for this thread
  for (int i = 0; i < K; ++i) {
    int g = base + i;
    if (g < n) {
      u32 v = hist[g];
      hist[g] = run;
      run += v;
    }
  }
}

// ---- K5: stable radix scatter; final pass also materializes packed edges ----
__global__ __launch_bounds__(256) void scatter_kernel(const u64* __restrict__ src,
                                                      u64* __restrict__ dst,
                                                      const u32* __restrict__ hist,
                                                      int shift, int nBlocks,
                                                      const int* __restrict__ edges,
                                                      const u8* __restrict__ bnd,
                                                      u64* __restrict__ pack,
                                                      int E) {
  __shared__ u32 off[256];
  __shared__ u32 cw[4][256];
  int tid = threadIdx.x;
  off[tid] = hist[(size_t)tid * nBlocks + blockIdx.x];
  int lane = tid & 63, w = tid >> 6;
  int base = blockIdx.x * 1024;
  for (int k = 0; k < 4; ++k) {
    cw[0][tid] = 0; cw[1][tid] = 0; cw[2][tid] = 0; cw[3][tid] = 0;
    __syncthreads();
    u64 key = src[base + k * 256 + tid];
    int d = (int)((key >> shift) & 255);
    u64 m = ~0ull;
#pragma unroll
    for (int bit = 0; bit < 8; ++bit) {
      u64 bl = __ballot((d >> bit) & 1);
      m &= ((d >> bit) & 1) ? bl : ~bl;
    }
    u32 riw = (u32)__popcll(m & ((1ull << lane) - 1ull));  // stable rank in wave
    if (riw == 0) cw[w][d] = (u32)__popcll(m);
    __syncthreads();
    u32 r = riw;
    for (int ww = 0; ww < w; ++ww) r += cw[ww][d];
    u32 pos = off[d] + r;
    dst[pos] = key;
    if (pack) {
      u32 idx = (u32)key;
      u64 pk = 0x100000000ull;            // sentinel: nb=1 (never collapses)
      if (idx < (u32)E) {
        int vv0 = edges[idx], vv1 = edges[E + idx];
        u64 b = bnd[idx];
        pk = (u64)(u32)(vv0 | (vv1 << 16)) | (b << 32);
      }
      pack[pos] = pk;
    }
    __syncthreads();
    off[tid] += cw[0][tid] + cw[1][tid] + cw[2][tid] + cw[3][tid];
    __syncthreads();
  }
}

// ---- K6: serial greedy collapse, one wave ----
// Alive mask as a bit-array (1563 u32 words) + per-chunk tag array (u8).
// Clean chunk: 2 tag writes + 2 tag reads + 2 bitword reads, ONE lgkm wait,
// ballot, decide, atomicAnd kill. Tags never need restore (always written
// before read within a chunk). Flagged chunks add one closure round + a
// short serial loop over only the flagged lanes. The single threshold-
// sensitive chunk falls back to the exact 64-step sequential loop.
__global__ __launch_bounds__(64) void collapse_kernel(const u64* __restrict__ pack,
                                                      const int* __restrict__ tgt,
                                                      float* __restrict__ out,
                                                      int V, int E) {
  __shared__ u32 bits[1568];
  __shared__ u8 tag[50048];
  int lane = threadIdx.x;
  for (int i = lane; i < 1568; i += 64) bits[i] = 0xFFFFFFFFu;
  int target = tgt[0];
  int cnt = V;
  __syncthreads();
  int nch = (E + 63) / 64;
  u64 pk = (lane < E) ? pack[lane] : 0x100000000ull;
  for (int c = 0; c < nch; ++c) {
    if (cnt <= target) break;
    // 1-deep prefetch of next chunk's packed edge (independent, coalesced)
    int g2 = (c + 1) * 64 + lane;
    u64 pkn = (c + 1 < nch && g2 < E) ? pack[g2] : 0x100000000ull;
    int v0 = (int)(pk & 0xffff);
    int v1 = (int)((pk >> 16) & 0xffff);
    int nb = (int)((pk >> 32) & 1);
    // tag round 1 + alive read, single wait
    tag[v0] = (u8)lane;
    tag[v1] = (u8)lane;
    asm volatile("" ::: "memory");
    int r0 = tag[v0];
    int r1 = tag[v1];
    u32 w0 = bits[v0 >> 5];
    u32 w1 = bits[v1 >> 5];
    int m0 = (int)((w0 >> (v0 & 31)) & 1);
    int m1 = (int)((w1 >> (v1 & 31)) & 1);
    int mism = (r0 != lane) | (r1 != lane);
    u64 flags = __ballot(mism);
    int cand = m0 & m1 & (nb ^ 1);
    int doit, K;
    if (flags == 0) {
      doit = cand;
      K = (int)__popcll(__ballot(doit));
    } else {
      // closure round: losers rewrite so winners get flagged too
      if (mism) { tag[v0] = (u8)lane; tag[v1] = (u8)lane; }
      asm volatile("" ::: "memory");
      r0 = tag[v0];
      r1 = tag[v1];
      mism |= (r0 != lane) | (r1 != lane);
      flags = __ballot(mism);
      int pdo = cand & (mism ^ 1);
      K = (int)__popcll(__ballot(pdo));
      int fa0 = m0, fa1 = m1, sdo = 0;
      u64 fm = flags;
      while (fm) {                         // serial over flagged lanes only
        int j = (int)__builtin_ctzll(fm);
        fm &= fm - 1;
        int ccur = fa0 & fa1 & (nb ^ 1);
        int d = __builtin_amdgcn_readlane(ccur, j);
        int kv = __builtin_amdgcn_readlane(v1, j);
        K += d;
        fa0 &= 1 ^ (d & (v0 == kv));
        fa1 &= 1 ^ (d & (v1 == kv));
        sdo = (lane == j) ? d : sdo;
      }
      doit = mism ? sdo : pdo;
    }
    if (cnt - K >= target) {               // bulk apply is order-exact here
      if (doit) atomicAnd(&bits[v1 >> 5], ~(1u << (v1 & 31)));
      cnt -= K;
    } else {
      // threshold-sensitive chunk (once): exact sequential semantics
      int a0 = m0, a1 = m1, myDo = 0;
#pragma unroll
      for (int j = 0; j < 64; ++j) {
        int candj = (cnt > target) & a0 & a1 & (nb ^ 1);
        int dj = __builtin_amdgcn_readlane(candj, j);
        int kv = __builtin_amdgcn_readlane(v1, j);
        cnt -= dj;
        a0 &= 1 ^ (dj & (v0 == kv));
        a1 &= 1 ^ (dj & (v1 == kv));
        myDo = (lane == j) ? dj : myDo;
      }
      if (myDo) atomicAnd(&bits[v1 >> 5], ~(1u << (v1 & 31)));
    }
    asm volatile("" ::: "memory");
    pk = pkn;
  }
  __syncthreads();
  for (int i = lane; i < V; i += 64)
    out[E + i] = ((bits[i >> 5] >> (i & 31)) & 1) ? 1.0f : 0.0f;
  if (lane == 0) out[E + V] = (float)cnt;
}

extern "C" void kernel_launch(void* const* d_in, const int* in_sizes, int n_in,
                              void* d_out, int out_size, void* d_ws, size_t ws_size,
                              hipStream_t stream) {
  const float* image = (const float*)d_in[0];
  const float* vs    = (const float*)d_in[1];
  const int*   edges = (const int*)d_in[2];
  const int*   tgt   = (const int*)d_in[3];
  int V = in_sizes[1] / 2;             // 50000
  int E = in_sizes[2] / 2;             // 150000
  int F = in_sizes[0] / V;             // 128
  int Npad = ((E + 1023) / 1024) * 1024;   // 150528
  int B = Npad / 1024;                 // 147 radix blocks

  // workspace layout (~4.2 MB)
  char* ws = (char*)d_ws;
  u64* keysA = (u64*)ws;
  u64* keysB = (u64*)(ws + (size_t)Npad * 8);
  u64* pack  = (u64*)(ws + (size_t)Npad * 16);
  float* nrm = (float*)(ws + (size_t)Npad * 24);
  u8*  bnd   = (u8*) (ws + (size_t)Npad * 24 + (size_t)V * 4);
  u32* hist  = (u32*)(ws + (size_t)Npad * 24 + (size_t)V * 4 + (size_t)Npad);
  float* out = (float*)d_out;

  int gpv = 256 / RW;
  vnorm_kernel<<<dim3((V + gpv - 1) / gpv), dim3(256), 0, stream>>>(image, nrm, V, F);
  edge_kernel<<<dim3(Npad / 256), dim3(256), 0, stream>>>(nrm, vs, edges, keysA, bnd, out, E, Npad);

  u64* src = keysA; u64* dst = keysB;
  for (int p = 0; p < 4; ++p) {
    int shift = 32 + 8 * p;            // stable LSD on the sq bits only
    hist_kernel<<<dim3(B), dim3(256), 0, stream>>>(src, hist, shift, B);
    scan_kernel<<<dim3(1), dim3(1024), 0, stream>>>(hist, 256 * B);
    scatter_kernel<<<dim3(B), dim3(256), 0, stream>>>(src, dst, hist, shift, B,
                                                      edges, bnd,
                                                      (p == 3) ? pack : (u64*)nullptr, E);
    u64* t = src; src = dst; dst = t;
  }
  collapse_kernel<<<dim3(1), dim3(64), 0, stream>>>(pack, tgt, out, V, E);
}

// Round 4
// 646.751 us; speedup vs baseline: 8.4709x; 1.5856x over previous
//
#include <hip/hip_runtime.h>
#include <hip/hip_bf16.h>
#include <stdint.h>

typedef unsigned int u32;
typedef unsigned long long u64;
typedef unsigned char u8;
typedef unsigned short u16;

// ---------------------------------------------------------------------------
// Reduction order for n[v] = sum_f image[v,f]^2 bit-matches the XLA:CPU
// reference (H1: stride-8 partials + halving combine; verified PASS R1-R3).
// DO NOT change RW/HALVING: vertex_mask correctness depends on exact rounding.
// ---------------------------------------------------------------------------
#define RW 8
#define HALVING 1

// ---- K1: per-vertex squared norm ----
__global__ __launch_bounds__(256) void vnorm_kernel(const float* __restrict__ image,
                                                    float* __restrict__ nrm,
                                                    int V, int F) {
#pragma clang fp contract(off)
  const int gpv = 256 / RW;
  int g = threadIdx.x / RW;
  int l = threadIdx.x % RW;
  int v = blockIdx.x * gpv + g;
  if (v >= V) return;
  const float* row = image + (size_t)v * F;
  int terms = F / RW;
  float x = row[l];
  float a = x * x;
  for (int i = 1; i < terms; ++i) {
    float y = row[i * RW + l];
    a = a + y * y;
  }
#if RW > 1
#if HALVING
#pragma unroll
  for (int d = RW / 2; d >= 1; d >>= 1) a = a + __shfl_xor(a, d);
#else
#pragma unroll
  for (int d = 1; d < RW; d <<= 1) a = a + __shfl_xor(a, d);
#endif
#endif
  if (l == 0) nrm[v] = a;
}

// ---- K2: per-edge priority, sort key, boundary flag ----
__global__ __launch_bounds__(256) void edge_kernel(const float* __restrict__ nrm,
                                                   const float* __restrict__ vs,
                                                   const int* __restrict__ edges,
                                                   u64* __restrict__ keys,
                                                   u8* __restrict__ bnd,
                                                   float* __restrict__ out_sq,
                                                   int E, int Npad) {
#pragma clang fp contract(off)
  int e = blockIdx.x * 256 + threadIdx.x;
  if (e >= Npad) return;
  u64 key = ~0ull;                         // sentinel sorts last
  if (e < E) {
    int v0 = edges[e], v1 = edges[E + e];
    float sq = nrm[v0] + nrm[v1];
    out_sq[e] = sq;
    key = ((u64)__float_as_uint(sq) << 32) | (u32)e;
    float ax = vs[2 * v0], ay = vs[2 * v0 + 1];
    float bx = vs[2 * v1], by = vs[2 * v1 + 1];
    const float lo = 0.01f, hi = 0.99f;
    bool b = (ax < lo) | (ax > hi) | (ay < lo) | (ay > hi)
           | (bx < lo) | (bx > hi) | (by < lo) | (by > hi);
    bnd[e] = b ? 1 : 0;
  }
  keys[e] = key;
}

// ---- K3: radix histogram ----
__global__ __launch_bounds__(256) void hist_kernel(const u64* __restrict__ src,
                                                   u32* __restrict__ hist,
                                                   int shift, int nBlocks) {
  __shared__ u32 c[256];
  c[threadIdx.x] = 0;
  __syncthreads();
  int base = blockIdx.x * 1024;
  for (int k = 0; k < 4; ++k) {
    u64 key = src[base + k * 256 + threadIdx.x];
    int d = (int)((key >> shift) & 255);
    atomicAdd(&c[d], 1u);
  }
  __syncthreads();
  hist[(size_t)threadIdx.x * nBlocks + blockIdx.x] = c[threadIdx.x];
}

// ---- K4: flat exclusive scan of the [256][B] digit-major histogram ----
__global__ __launch_bounds__(1024) void scan_kernel(u32* __restrict__ hist, int n) {
  __shared__ u32 wsum[16];
  int tid = threadIdx.x;
  int K = (n + 1023) / 1024;
  int base = tid * K;
  u32 s = 0;
  for (int i = 0; i < K; ++i) {
    int g = base + i;
    if (g < n) s += hist[g];
  }
  int lane = tid & 63, wv = tid >> 6;
  u32 inc = s;
#pragma unroll
  for (int d = 1; d < 64; d <<= 1) {
    u32 t = __shfl_up(inc, d);
    if (lane >= d) inc += t;
  }
  if (lane == 63) wsum[wv] = inc;
  __syncthreads();
  if (wv == 0) {
    u32 w0 = (lane < 16) ? wsum[lane] : 0;
    u32 winc = w0;
#pragma unroll
    for (int d = 1; d < 16; d <<= 1) {
      u32 t = __shfl_up(winc, d);
      if (lane >= d) winc += t;
    }
    if (lane < 16) wsum[lane] = winc - w0;
  }
  __syncthreads();
  u32 run = wsum[wv] + (inc - s);
  for (int i = 0; i < K; ++i) {
    int g = base + i;
    if (g < n) {
      u32 v = hist[g];
      hist[g] = run;
      run += v;
    }
  }
}

// ---- K5: stable radix scatter; final pass materializes packed edges ----
// pack entry: v0 | v1<<16 | nb<<32 | intraflag<<33 | hz<<34 (flags set later)
__global__ __launch_bounds__(256) void scatter_kernel(const u64* __restrict__ src,
                                                      u64* __restrict__ dst,
                                                      const u32* __restrict__ hist,
                                                      int shift, int nBlocks,
                                                      const int* __restrict__ edges,
                                                      const u8* __restrict__ bnd,
                                                      u64* __restrict__ pack,
                                                      int E, int V) {
  __shared__ u32 off[256];
  __shared__ u32 cw[4][256];
  int tid = threadIdx.x;
  off[tid] = hist[(size_t)tid * nBlocks + blockIdx.x];
  int lane = tid & 63, w = tid >> 6;
  int base = blockIdx.x * 1024;
  for (int k = 0; k < 4; ++k) {
    cw[0][tid] = 0; cw[1][tid] = 0; cw[2][tid] = 0; cw[3][tid] = 0;
    __syncthreads();
    u64 key = src[base + k * 256 + tid];
    int d = (int)((key >> shift) & 255);
    u64 m = ~0ull;
#pragma unroll
    for (int bit = 0; bit < 8; ++bit) {
      u64 bl = __ballot((d >> bit) & 1);
      m &= ((d >> bit) & 1) ? bl : ~bl;
    }
    u32 riw = (u32)__popcll(m & ((1ull << lane) - 1ull));
    if (riw == 0) cw[w][d] = (u32)__popcll(m);
    __syncthreads();
    u32 r = riw;
    for (int ww = 0; ww < w; ++ww) r += cw[ww][d];
    u32 pos = off[d] + r;
    dst[pos] = key;
    if (pack) {
      u32 idx = (u32)key;
      u64 pk;
      if (idx < (u32)E) {
        int vv0 = edges[idx], vv1 = edges[E + idx];
        u64 b = bnd[idx];
        pk = (u64)(u32)(vv0 | (vv1 << 16)) | (b << 32);
      } else {
        // sentinel: distinct unused verts per position (disjoint between
        // adjacent chunks), nb=1 so it never collapses
        u32 sv0 = (u32)V + ((pos & 255u) << 1);
        pk = (u64)(sv0 | ((sv0 + 1) << 16)) | (1ull << 32);
      }
      pack[pos] = pk;
    }
    __syncthreads();
    off[tid] += cw[0][tid] + cw[1][tid] + cw[2][tid] + cw[3][tid];
    __syncthreads();
  }
}

// ---- K5b: precompute conflict flags per 128-edge chunk ----
// intra flag: edge's v0 or v1 occurs >1x among the chunk's 256 vertex slots
// hz flag (bit34 of chunk's first entry): any v1 of chunk c appears among
// chunk c+1's vertices (governs read-vs-kill ordering in collapse).
// Benign race: neighbor blocks read our pack entries while we OR in bits
// 33/34 -- they only use bits 0-31, and aligned 8B stores are not torn.
__global__ __launch_bounds__(64) void flag_kernel(u64* __restrict__ pack, int nch) {
  __shared__ u32 vv[256];
  __shared__ u32 vn[256];
  int c = blockIdx.x;
  int lane = threadIdx.x;
  size_t base = (size_t)c * 128;
  u64 pk0 = pack[base + lane];
  u64 pk1 = pack[base + 64 + lane];
  u32 va0 = (u32)(pk0 & 0xffff), va1 = (u32)((pk0 >> 16) & 0xffff);
  u32 vb0 = (u32)(pk1 & 0xffff), vb1 = (u32)((pk1 >> 16) & 0xffff);
  vv[lane] = va0; vv[64 + lane] = va1;
  vv[128 + lane] = vb0; vv[192 + lane] = vb1;
  int haveNext = (c + 1 < nch);
  if (haveNext) {
    u64 q0 = pack[base + 128 + lane];
    u64 q1 = pack[base + 192 + lane];
    vn[lane] = (u32)(q0 & 0xffff); vn[64 + lane] = (u32)((q0 >> 16) & 0xffff);
    vn[128 + lane] = (u32)(q1 & 0xffff); vn[192 + lane] = (u32)((q1 >> 16) & 0xffff);
  }
  __syncthreads();
  int ca0 = 0, ca1 = 0, cb0 = 0, cb1 = 0;
  for (int i = 0; i < 256; ++i) {
    u32 x = vv[i];
    ca0 += (x == va0); ca1 += (x == va1);
    cb0 += (x == vb0); cb1 += (x == vb1);
  }
  int flA = (ca0 > 1) | (ca1 > 1);
  int flB = (cb0 > 1) | (cb1 > 1);
  int hzHit = 0;
  if (haveNext) {
    for (int i = 0; i < 256; ++i) {
      u32 x = vn[i];
      hzHit |= (x == va1) | (x == vb1);
    }
  }
  u64 hzAny = __ballot(hzHit);
  pk0 |= (u64)flA << 33;
  pk1 |= (u64)flB << 33;
  if (lane == 0 && hzAny != 0) pk0 |= 1ull << 34;
  pack[base + lane] = pk0;
  pack[base + 64 + lane] = pk1;
}

// ---- K6: serial greedy collapse, one wave, 128 edges/chunk (2 per lane) ----
// All conflict detection precomputed (flag_kernel). Per chunk: use mask words
// read last chunk, ballot-decide, serial only over flagged lanes; issue next
// chunk's 4 LDS reads BEFORE this chunk's kills when hz==0 (DS pipe is
// in-order per wave, and hz==0 certifies disjointness). Global pack loads
// prefetched one 8-chunk superchunk (~1024 edges) ahead in named registers.
#define STAGE(PK0, PK1, NPK0, NPK1)                                           \
  do {                                                                        \
    if (done) break;                                                          \
    u64 _pk0 = (PK0), _pk1 = (PK1);                                           \
    int v0a = (int)(_pk0 & 0xffff), v1a = (int)((_pk0 >> 16) & 0xffff);       \
    int nba = (int)((_pk0 >> 32) & 1), fla = (int)((_pk0 >> 33) & 1);         \
    int v0b = (int)(_pk1 & 0xffff), v1b = (int)((_pk1 >> 16) & 0xffff);       \
    int nbb = (int)((_pk1 >> 32) & 1), flb = (int)((_pk1 >> 33) & 1);         \
    int hz = (int)((__builtin_amdgcn_readlane((u32)(_pk0 >> 32), 0) >> 2) & 1); \
    int m0a = (int)((w0a >> (v0a & 31)) & 1);                                 \
    int m1a = (int)((w1a >> (v1a & 31)) & 1);                                 \
    int m0b = (int)((w0b >> (v0b & 31)) & 1);                                 \
    int m1b = (int)((w1b >> (v1b & 31)) & 1);                                 \
    int candA = m0a & m1a & (nba ^ 1);                                        \
    int candB = m0b & m1b & (nbb ^ 1);                                        \
    u64 fA = __ballot(fla), fB = __ballot(flb);                               \
    int doA, doB, K;                                                          \
    if ((fA | fB) == 0) {                                                     \
      doA = candA; doB = candB;                                               \
      K = (int)__popcll(__ballot(candA)) + (int)__popcll(__ballot(candB));    \
    } else {                                                                  \
      int pdoA = candA & (fla ^ 1), pdoB = candB & (flb ^ 1);                 \
      K = (int)__popcll(__ballot(pdoA)) + (int)__popcll(__ballot(pdoB));      \
      int pa0 = m0a, pa1 = m1a, pb0 = m0b, pb1 = m1b;                         \
      int sdoA = 0, sdoB = 0;                                                 \
      u64 t = fA;                                                             \
      while (t) {                                                             \
        int j = (int)__builtin_ctzll(t); t &= t - 1;                          \
        int cc = pa0 & pa1 & (nba ^ 1);                                       \
        int d = __builtin_amdgcn_readlane(cc, j);                             \
        int kv = __builtin_amdgcn_readlane(v1a, j);                           \
        K += d;                                                               \
        pa0 &= 1 ^ (d & (v0a == kv)); pa1 &= 1 ^ (d & (v1a == kv));           \
        pb0 &= 1 ^ (d & (v0b == kv)); pb1 &= 1 ^ (d & (v1b == kv));           \
        sdoA = (lane == j) ? d : sdoA;                                        \
      }                                                                       \
      t = fB;                                                                 \
      while (t) {                                                             \
        int j = (int)__builtin_ctzll(t); t &= t - 1;                          \
        int cc = pb0 & pb1 & (nbb ^ 1);                                       \
        int d = __builtin_amdgcn_readlane(cc, j);                             \
        int kv = __builtin_amdgcn_readlane(v1b, j);                           \
        K += d;                                                               \
        pa0 &= 1 ^ (d & (v0a == kv)); pa1 &= 1 ^ (d & (v1a == kv));           \
        pb0 &= 1 ^ (d & (v0b == kv)); pb1 &= 1 ^ (d & (v1b == kv));           \
        sdoB = (lane == j) ? d : sdoB;                                        \
      }                                                                       \
      doA = fla ? sdoA : pdoA;                                                \
      doB = flb ? sdoB : pdoB;                                                \
    }                                                                         \
    if (cnt - K >= target) {                                                  \
      cnt -= K;                                                               \
      int nv0a = (int)((NPK0) & 0xffff), nv1a = (int)(((NPK0) >> 16) & 0xffff); \
      int nv0b = (int)((NPK1) & 0xffff), nv1b = (int)(((NPK1) >> 16) & 0xffff); \
      if (hz == 0) {                                                          \
        w0a = bits[nv0a >> 5]; w1a = bits[nv1a >> 5];                         \
        w0b = bits[nv0b >> 5]; w1b = bits[nv1b >> 5];                         \
        if (doA) atomicAnd(&bits[v1a >> 5], ~(1u << (v1a & 31)));             \
        if (doB) atomicAnd(&bits[v1b >> 5], ~(1u << (v1b & 31)));             \
      } else {                                                                \
        if (doA) atomicAnd(&bits[v1a >> 5], ~(1u << (v1a & 31)));             \
        if (doB) atomicAnd(&bits[v1b >> 5], ~(1u << (v1b & 31)));             \
        asm volatile("" ::: "memory");                                        \
        w0a = bits[nv0a >> 5]; w1a = bits[nv1a >> 5];                         \
        w0b = bits[nv0b >> 5]; w1b = bits[nv1b >> 5];                         \
      }                                                                       \
      if (cnt <= target) done = 1;                                            \
    } else {                                                                  \
      int a0a = m0a, a1a = m1a, a0b = m0b, a1b = m1b;                         \
      doA = 0; doB = 0;                                                       \
      for (int j = 0; j < 64; ++j) {                                          \
        int cc = (cnt > target) & a0a & a1a & (nba ^ 1);                      \
        int d = __builtin_amdgcn_readlane(cc, j);                             \
        int kv = __builtin_amdgcn_readlane(v1a, j);                           \
        cnt -= d;                                                             \
        a0a &= 1 ^ (d & (v0a == kv)); a1a &= 1 ^ (d & (v1a == kv));           \
        a0b &= 1 ^ (d & (v0b == kv)); a1b &= 1 ^ (d & (v1b == kv));           \
        doA = (lane == j) ? d : doA;                                          \
      }                                                                       \
      for (int j = 0; j < 64; ++j) {                                          \
        int cc = (cnt > target) & a0b & a1b & (nbb ^ 1);                      \
        int d = __builtin_amdgcn_readlane(cc, j);                             \
        int kv = __builtin_amdgcn_readlane(v1b, j);                           \
        cnt -= d;                                                             \
        a0a &= 1 ^ (d & (v0a == kv)); a1a &= 1 ^ (d & (v1a == kv));           \
        a0b &= 1 ^ (d & (v0b == kv)); a1b &= 1 ^ (d & (v1b == kv));           \
        doB = (lane == j) ? d : doB;                                          \
      }                                                                       \
      if (doA) atomicAnd(&bits[v1a >> 5], ~(1u << (v1a & 31)));               \
      if (doB) atomicAnd(&bits[v1b >> 5], ~(1u << (v1b & 31)));               \
      done = 1;                                                               \
    }                                                                         \
  } while (0)

__global__ __launch_bounds__(64) void collapse_kernel(const u64* __restrict__ pack,
                                                      const int* __restrict__ tgt,
                                                      float* __restrict__ out,
                                                      u32* __restrict__ gbits,
                                                      int V, int E, int nsc) {
  __shared__ u32 bits[1600];
  int lane = threadIdx.x;
  for (int i = lane; i < 1600; i += 64) bits[i] = 0xFFFFFFFFu;
  int target = tgt[0];
  int cnt = V;
  int done = 0;
  const u64* p = pack;
  u64 c0a = p[lane +   0], c0b = p[lane +  64];
  u64 c1a = p[lane + 128], c1b = p[lane + 192];
  u64 c2a = p[lane + 256], c2b = p[lane + 320];
  u64 c3a = p[lane + 384], c3b = p[lane + 448];
  u64 c4a = p[lane + 512], c4b = p[lane + 576];
  u64 c5a = p[lane + 640], c5b = p[lane + 704];
  u64 c6a = p[lane + 768], c6b = p[lane + 832];
  u64 c7a = p[lane + 896], c7b = p[lane + 960];
  // initial LDS reads for chunk 0 (ordered after init writes by DS FIFO)
  u32 w0a = bits[(int)(c0a & 0xffff) >> 5];
  u32 w1a = bits[(int)((c0a >> 16) & 0xffff) >> 5];
  u32 w0b = bits[(int)(c0b & 0xffff) >> 5];
  u32 w1b = bits[(int)((c0b >> 16) & 0xffff) >> 5];
  for (int s = 0; s < nsc; ++s) {
    const u64* np = pack + (size_t)((s + 1 < nsc) ? (s + 1) : s) * 1024;
    u64 n0a = np[lane +   0], n0b = np[lane +  64];
    u64 n1a = np[lane + 128], n1b = np[lane + 192];
    u64 n2a = np[lane + 256], n2b = np[lane + 320];
    u64 n3a = np[lane + 384], n3b = np[lane + 448];
    u64 n4a = np[lane + 512], n4b = np[lane + 576];
    u64 n5a = np[lane + 640], n5b = np[lane + 704];
    u64 n6a = np[lane + 768], n6b = np[lane + 832];
    u64 n7a = np[lane + 896], n7b = np[lane + 960];
    STAGE(c0a, c0b, c1a, c1b);
    STAGE(c1a, c1b, c2a, c2b);
    STAGE(c2a, c2b, c3a, c3b);
    STAGE(c3a, c3b, c4a, c4b);
    STAGE(c4a, c4b, c5a, c5b);
    STAGE(c5a, c5b, c6a, c6b);
    STAGE(c6a, c6b, c7a, c7b);
    STAGE(c7a, c7b, n0a, n0b);
    c0a = n0a; c0b = n0b; c1a = n1a; c1b = n1b;
    c2a = n2a; c2b = n2b; c3a = n3a; c3b = n3b;
    c4a = n4a; c4b = n4b; c5a = n5a; c5b = n5b;
    c6a = n6a; c6b = n6b; c7a = n7a; c7b = n7b;
    if (done) break;
  }
  asm volatile("" ::: "memory");
  for (int i = lane; i < 1600; i += 64) gbits[i] = bits[i];
  if (lane == 0) out[E + V] = (float)cnt;
}

// ---- K7: expand bit-mask to float outputs (parallel) ----
__global__ __launch_bounds__(256) void expand_kernel(const u32* __restrict__ gbits,
                                                     float* __restrict__ out,
                                                     int V, int E) {
  int i = blockIdx.x * 256 + threadIdx.x;
  if (i < V) out[E + i] = ((gbits[i >> 5] >> (i & 31)) & 1) ? 1.0f : 0.0f;
}

extern "C" void kernel_launch(void* const* d_in, const int* in_sizes, int n_in,
                              void* d_out, int out_size, void* d_ws, size_t ws_size,
                              hipStream_t stream) {
  const float* image = (const float*)d_in[0];
  const float* vs    = (const float*)d_in[1];
  const int*   edges = (const int*)d_in[2];
  const int*   tgt   = (const int*)d_in[3];
  int V = in_sizes[1] / 2;                 // 50000
  int E = in_sizes[2] / 2;                 // 150000
  int F = in_sizes[0] / V;                 // 128
  int Npad = ((E + 1023) / 1024) * 1024;   // 150528 (divisible by 1024)
  int B = Npad / 1024;                     // 147 radix blocks
  int nch = Npad / 128;                    // 1176 chunks
  int nsc = Npad / 1024;                   // 147 superchunks

  // workspace layout (~4.2 MB)
  char* ws = (char*)d_ws;
  u64* keysA = (u64*)ws;
  u64* keysB = (u64*)(ws + (size_t)Npad * 8);
  u64* pack  = (u64*)(ws + (size_t)Npad * 16);
  float* nrm = (float*)(ws + (size_t)Npad * 24);
  u8*  bnd   = (u8*) (ws + (size_t)Npad * 24 + (size_t)V * 4);
  u32* hist  = (u32*)(ws + (size_t)Npad * 24 + (size_t)V * 4 + (size_t)Npad);
  u32* gbits = (u32*)(ws + (size_t)Npad * 24 + (size_t)V * 4 + (size_t)Npad
                         + (size_t)256 * B * 4);
  float* out = (float*)d_out;

  int gpv = 256 / RW;
  vnorm_kernel<<<dim3((V + gpv - 1) / gpv), dim3(256), 0, stream>>>(image, nrm, V, F);
  edge_kernel<<<dim3(Npad / 256), dim3(256), 0, stream>>>(nrm, vs, edges, keysA, bnd, out, E, Npad);

  u64* src = keysA; u64* dst = keysB;
  for (int p = 0; p < 4; ++p) {
    int shift = 32 + 8 * p;
    hist_kernel<<<dim3(B), dim3(256), 0, stream>>>(src, hist, shift, B);
    scan_kernel<<<dim3(1), dim3(1024), 0, stream>>>(hist, 256 * B);
    scatter_kernel<<<dim3(B), dim3(256), 0, stream>>>(src, dst, hist, shift, B,
                                                      edges, bnd,
                                                      (p == 3) ? pack : (u64*)nullptr,
                                                      E, V);
    u64* t = src; src = dst; dst = t;
  }
  flag_kernel<<<dim3(nch), dim3(64), 0, stream>>>(pack, nch);
  collapse_kernel<<<dim3(1), dim3(64), 0, stream>>>(pack, tgt, out, gbits, V, E, nsc);
  expand_kernel<<<dim3((V + 255) / 256), dim3(256), 0, stream>>>(gbits, out, V, E);
}